// Round 7
// baseline (266.289 us; speedup 1.0000x reference)
//
#include <hip/hip_runtime.h>

#define N_NODES 100000
#define N_EDGES 1200000
#define N_GRAPHS 256
#define IN_C 5
#define HID_C 64
#define OUT_C 2

#define BSH 7
#define BNODES 128
#define NB ((N_NODES + BNODES - 1) / BNODES)        // 782
#define CAPB 2048                                   // fixed bucket capacity (E=1534, sigma=39)
#define EPB 2048                                    // edges per block (binning)
#define NBLK_E ((N_EDGES + EPB - 1) / EPB)          // 586
#define GNPW 8                                      // nodes per wave in fused gather2+pool
#define L1NPW 8                                     // nodes per wave in k_l1

typedef unsigned int uint32;

// fp32 -> bf16 round-to-nearest-even (returns 16-bit pattern)
__device__ __forceinline__ uint32 f2bf(float f) {
    uint32 x = __float_as_uint(f);
    return (x + 0x7FFFu + ((x >> 16) & 1u)) >> 16;
}
__device__ __forceinline__ float bflo(uint32 r) { return __uint_as_float(r << 16); }
__device__ __forceinline__ float bfhi(uint32 r) { return __uint_as_float(r & 0xFFFF0000u); }

// ---- bin edges into fixed-capacity bucket regions, packed (dst_local<<17)|src.
// Blocks 0..63 also zero the pooled accumulator (consumed later by k_gather2p).
__global__ void k_bscatter(const int* __restrict__ src, const int* __restrict__ dst,
                           int* __restrict__ bcnt, int* __restrict__ pairs,
                           float* __restrict__ pooled) {
    __shared__ int h[NB];
    if (blockIdx.x < (N_GRAPHS * HID_C) / 256)
        pooled[blockIdx.x * 256 + threadIdx.x] = 0.f;
    for (int i = threadIdx.x; i < NB; i += blockDim.x) h[i] = 0;
    __syncthreads();
    int e0 = blockIdx.x * EPB;
    int e1 = e0 + EPB; if (e1 > N_EDGES) e1 = N_EDGES;
    for (int e = e0 + threadIdx.x; e < e1; e += blockDim.x)
        atomicAdd(&h[dst[e] >> BSH], 1);
    __syncthreads();
    for (int i = threadIdx.x; i < NB; i += blockDim.x)
        if (h[i]) h[i] = (i << 11) + atomicAdd(&bcnt[i], h[i]);
    __syncthreads();
    for (int e = e0 + threadIdx.x; e < e1; e += blockDim.x) {
        int d = dst[e];
        int pos = atomicAdd(&h[d >> BSH], 1);
        pairs[pos] = ((d & (BNODES - 1)) << 17) | src[e];
    }
}

// ---- per-bucket counting sort -> CSR + rs/cnt/dinv, epilogue writes
// xs[node] = x[node] * dinv[node]  (fp32, rows padded to 8 floats).
__global__ void k_bsort_xs(const int* __restrict__ pairs, const int* __restrict__ bcnt,
                           const float* __restrict__ x,
                           int* __restrict__ csr, int* __restrict__ rs,
                           int* __restrict__ cnt, float* __restrict__ dinv,
                           float* __restrict__ xs) {
    __shared__ int hist[BNODES];
    __shared__ int tmp[BNODES];
    __shared__ int cur[BNODES];
    __shared__ float sdv[BNODES];
    int b = blockIdx.x;
    int t = threadIdx.x;
    int base = b << BSH;
    if (t < BNODES) hist[t] = 0;
    __syncthreads();
    int s = b << 11;            // fixed bucket start
    int n = bcnt[b];
    for (int i = t; i < n; i += 256)
        atomicAdd(&hist[pairs[s + i] >> 17], 1);
    __syncthreads();
    int v = (t < BNODES) ? hist[t] : 0;
    if (t < BNODES) tmp[t] = v;
    __syncthreads();
    for (int off = 1; off < BNODES; off <<= 1) {
        int a = (t < BNODES && t >= off) ? tmp[t - off] : 0;
        __syncthreads();
        if (t < BNODES) tmp[t] += a;
        __syncthreads();
    }
    float dv_t = rsqrtf((float)v + 1.0f);
    if (t < BNODES) {
        cur[t] = tmp[t] - v;
        sdv[t] = dv_t;
        if (base + t < N_NODES) {
            rs[base + t] = s + tmp[t] - v;
            cnt[base + t] = v;
            dinv[base + t] = dv_t;
        }
    }
    __syncthreads();
    for (int i = t; i < n; i += 256) {
        int p = pairs[s + i];
        int pos = atomicAdd(&cur[p >> 17], 1);
        csr[s + pos] = p & 0x1FFFF;
    }
    // ---- xs epilogue: xs[node*8+k] = x[node*5+k] * dinv[node], k<5 ----
    for (int i = t; i < BNODES * 8; i += 256) {
        int nl = i >> 3, k = i & 7;
        int node = base + nl;
        if (node < N_NODES && k < IN_C)
            xs[(unsigned)node * 8 + k] = x[(unsigned)node * IN_C + k] * sdv[nl];
    }
}

// ---- fused layer-1: 5-dim gather (L2-resident xs table) + @W1 + relu + @W2,
// writes g2tab (bf16x2 packed). W1/W2 columns live in REGISTERS (each lane
// owns a fixed channel pair), h-row bounces through LDS as broadcast b128 reads.
__global__ void __launch_bounds__(256) k_l1(
        const float* __restrict__ xs, const int* __restrict__ csr,
        const int* __restrict__ rs, const int* __restrict__ cnt,
        const float* __restrict__ dinv, const float* __restrict__ b1,
        const float* __restrict__ W1, const float* __restrict__ W2,
        uint32* __restrict__ g2t) {
    __shared__ __align__(16) float sagg[4][L1NPW][8];   // 1 KB
    __shared__ __align__(16) float srow[4][2][HID_C];   // 2 KB
    int tid = threadIdx.x;
    int w = tid >> 6;
    int lane = tid & 63;
    int base = (blockIdx.x * 4 + w) * L1NPW;

    // ---- gather phase: 8 lanes per node, fp32 5-vec accumulate (pipelined) ----
    int g = lane >> 3, l = lane & 7;
    int v = base + g;
    float a0 = 0.f, a1 = 0.f, a2 = 0.f, a3 = 0.f, a4 = 0.f;
    if (v < N_NODES) {
        int k0 = rs[v];
        int n = cnt[v];
        if (l == 0) {           // self-loop contribution
            float4 p = *(const float4*)&xs[(unsigned)v * 8];
            a0 = p.x; a1 = p.y; a2 = p.z; a3 = p.w;
            a4 = xs[(unsigned)v * 8 + 4];
        }
        int i = l;
        int un = (i < n) ? csr[k0 + i] : -1;
        while (un >= 0) {
            int u = un;
            i += 8;
            un = (i < n) ? csr[k0 + i] : -1;   // next csr overlaps this xs gather
            float4 p = *(const float4*)&xs[(unsigned)u * 8];
            float p4 = xs[(unsigned)u * 8 + 4];
            a0 += p.x; a1 += p.y; a2 += p.z; a3 += p.w; a4 += p4;
        }
    }
#pragma unroll
    for (int off = 4; off; off >>= 1) {
        a0 += __shfl_xor(a0, off);
        a1 += __shfl_xor(a1, off);
        a2 += __shfl_xor(a2, off);
        a3 += __shfl_xor(a3, off);
        a4 += __shfl_xor(a4, off);
    }
    if (l == 0 && v < N_NODES) {
        *(float4*)&sagg[w][g][0] = make_float4(a0, a1, a2, a3);
        sagg[w][g][4] = a4;
    }

    // ---- weight columns -> registers (static indexing only) ----
    int half = lane >> 5, c2 = lane & 31;
    int kb = half << 5;
    float2 w1r[IN_C];
#pragma unroll
    for (int k = 0; k < IN_C; ++k)
        w1r[k] = *(const float2*)&W1[k * HID_C + 2 * c2];
    float2 w2r[32];
#pragma unroll
    for (int j = 0; j < 32; ++j)
        w2r[j] = *(const float2*)&W2[(kb + j) * HID_C + 2 * c2];
    float2 bias = *(const float2*)&b1[2 * c2];

    // ---- dense phase: h1 = relu(dinv*(agg@W1)+b1); g2 = bf16(dinv*(h1@W2)) ----
    for (int gg = 0; gg < L1NPW; ++gg) {
        int node = base + gg;                 // base wave-uniform -> uniform break
        if (node >= N_NODES) break;
        float dv = dinv[node];
        float4 qa = *(const float4*)&sagg[w][gg][0];
        float q4 = sagg[w][gg][4];
        float s0 = qa.x * w1r[0].x + qa.y * w1r[1].x + qa.z * w1r[2].x
                 + qa.w * w1r[3].x + q4 * w1r[4].x;
        float s1 = qa.x * w1r[0].y + qa.y * w1r[1].y + qa.z * w1r[2].y
                 + qa.w * w1r[3].y + q4 * w1r[4].y;
        float h0 = fmaxf(s0 * dv + bias.x, 0.f);
        float h1 = fmaxf(s1 * dv + bias.y, 0.f);
        int buf = gg & 1;
        if (half == 0) *(float2*)&srow[w][buf][2 * c2] = make_float2(h0, h1);
        float t0 = 0.f, t1 = 0.f;
#pragma unroll
        for (int jj = 0; jj < 8; ++jj) {
            float4 hv = *(const float4*)&srow[w][buf][kb + 4 * jj];  // broadcast
            t0 += hv.x * w2r[4 * jj + 0].x + hv.y * w2r[4 * jj + 1].x
                + hv.z * w2r[4 * jj + 2].x + hv.w * w2r[4 * jj + 3].x;
            t1 += hv.x * w2r[4 * jj + 0].y + hv.y * w2r[4 * jj + 1].y
                + hv.z * w2r[4 * jj + 2].y + hv.w * w2r[4 * jj + 3].y;
        }
        t0 += __shfl_xor(t0, 32);
        t1 += __shfl_xor(t1, 32);
        if (half == 0)
            g2t[(unsigned)node * 32 + c2] = (f2bf(t1 * dv) << 16) | f2bf(t0 * dv);
    }
}

// ---- gather layer 2 fused with relu + mean-pool accumulate.
// v3: FOUR nodes per wave (16 lanes each, uint2 = 4 channels per lane).
// One gather instruction covers 4 rows (512 B) -> 2x rows-in-flight vs v2.
// __launch_bounds__(256,4): 128-VGPR budget so the 8-deep chunk stays in flight
// (v2's bare launch_bounds let the compiler shrink to 24 VGPR and serialize).
// Note: 12500 waves x 8 nodes == N_NODES exactly -> all waves full, no guards.
__global__ void __launch_bounds__(256, 4) k_gather2p(
        const uint32* __restrict__ g, const int* __restrict__ csr,
        const int* __restrict__ rs, const int* __restrict__ cnt,
        const float* __restrict__ dinv, const float* __restrict__ b,
        const int* __restrict__ batch, float* __restrict__ pooled) {
    int wv = __builtin_amdgcn_readfirstlane(
        blockIdx.x * (blockDim.x >> 6) + (threadIdx.x >> 6));
    int n0 = wv * GNPW;
    if (n0 >= N_NODES) return;
    int lane = threadIdx.x & 63;
    int sub = lane >> 4;                  // node slot within quad (0..3)
    int c4 = lane & 15;                   // channel-quad index (4 channels)
    float4 bias = *(const float4*)&b[4 * c4];
    float p0 = 0.f, p1 = 0.f, p2 = 0.f, p3 = 0.f;
    int curg = -1;                        // per-lane graph-run accumulator
#pragma unroll
    for (int it = 0; it < GNPW / 4; ++it) {
        int v = n0 + it * 4 + sub;
        int k0 = rs[v];
        int n = cnt[v];
        uint2 rr = *(const uint2*)&g[(unsigned)v * 32 + 2 * c4];   // self-loop
        float s0 = bflo(rr.x), s1 = bfhi(rr.x), s2 = bflo(rr.y), s3 = bfhi(rr.y);
        int i = 0;
        for (; i + 7 < n; i += 8) {
            int u0 = csr[k0 + i + 0], u1 = csr[k0 + i + 1];
            int u2 = csr[k0 + i + 2], u3 = csr[k0 + i + 3];
            int u4 = csr[k0 + i + 4], u5 = csr[k0 + i + 5];
            int u6 = csr[k0 + i + 6], u7 = csr[k0 + i + 7];
            uint2 r0 = *(const uint2*)&g[(unsigned)u0 * 32 + 2 * c4];
            uint2 r1 = *(const uint2*)&g[(unsigned)u1 * 32 + 2 * c4];
            uint2 r2 = *(const uint2*)&g[(unsigned)u2 * 32 + 2 * c4];
            uint2 r3 = *(const uint2*)&g[(unsigned)u3 * 32 + 2 * c4];
            uint2 r4 = *(const uint2*)&g[(unsigned)u4 * 32 + 2 * c4];
            uint2 r5 = *(const uint2*)&g[(unsigned)u5 * 32 + 2 * c4];
            uint2 r6 = *(const uint2*)&g[(unsigned)u6 * 32 + 2 * c4];
            uint2 r7 = *(const uint2*)&g[(unsigned)u7 * 32 + 2 * c4];
            s0 += ((bflo(r0.x) + bflo(r1.x)) + (bflo(r2.x) + bflo(r3.x)))
                + ((bflo(r4.x) + bflo(r5.x)) + (bflo(r6.x) + bflo(r7.x)));
            s1 += ((bfhi(r0.x) + bfhi(r1.x)) + (bfhi(r2.x) + bfhi(r3.x)))
                + ((bfhi(r4.x) + bfhi(r5.x)) + (bfhi(r6.x) + bfhi(r7.x)));
            s2 += ((bflo(r0.y) + bflo(r1.y)) + (bflo(r2.y) + bflo(r3.y)))
                + ((bflo(r4.y) + bflo(r5.y)) + (bflo(r6.y) + bflo(r7.y)));
            s3 += ((bfhi(r0.y) + bfhi(r1.y)) + (bfhi(r2.y) + bfhi(r3.y)))
                + ((bfhi(r4.y) + bfhi(r5.y)) + (bfhi(r6.y) + bfhi(r7.y)));
        }
        for (; i + 3 < n; i += 4) {
            int u0 = csr[k0 + i + 0], u1 = csr[k0 + i + 1];
            int u2 = csr[k0 + i + 2], u3 = csr[k0 + i + 3];
            uint2 r0 = *(const uint2*)&g[(unsigned)u0 * 32 + 2 * c4];
            uint2 r1 = *(const uint2*)&g[(unsigned)u1 * 32 + 2 * c4];
            uint2 r2 = *(const uint2*)&g[(unsigned)u2 * 32 + 2 * c4];
            uint2 r3 = *(const uint2*)&g[(unsigned)u3 * 32 + 2 * c4];
            s0 += (bflo(r0.x) + bflo(r1.x)) + (bflo(r2.x) + bflo(r3.x));
            s1 += (bfhi(r0.x) + bfhi(r1.x)) + (bfhi(r2.x) + bfhi(r3.x));
            s2 += (bflo(r0.y) + bflo(r1.y)) + (bflo(r2.y) + bflo(r3.y));
            s3 += (bfhi(r0.y) + bfhi(r1.y)) + (bfhi(r2.y) + bfhi(r3.y));
        }
        for (; i < n; ++i) {
            uint2 r = *(const uint2*)&g[(unsigned)csr[k0 + i] * 32 + 2 * c4];
            s0 += bflo(r.x); s1 += bfhi(r.x);
            s2 += bflo(r.y); s3 += bfhi(r.y);
        }
        float dv = dinv[v];
        float o0 = fmaxf(s0 * dv + bias.x, 0.f);
        float o1 = fmaxf(s1 * dv + bias.y, 0.f);
        float o2 = fmaxf(s2 * dv + bias.z, 0.f);
        float o3 = fmaxf(s3 * dv + bias.w, 0.f);
        int gg = batch[v];
        if (gg != curg) {
            if (curg >= 0) {
                atomicAdd(&pooled[curg * HID_C + 4 * c4 + 0], p0);
                atomicAdd(&pooled[curg * HID_C + 4 * c4 + 1], p1);
                atomicAdd(&pooled[curg * HID_C + 4 * c4 + 2], p2);
                atomicAdd(&pooled[curg * HID_C + 4 * c4 + 3], p3);
            }
            p0 = 0.f; p1 = 0.f; p2 = 0.f; p3 = 0.f; curg = gg;
        }
        p0 += o0; p1 += o1; p2 += o2; p3 += o3;
    }
    if (curg >= 0) {
        atomicAdd(&pooled[curg * HID_C + 4 * c4 + 0], p0);
        atomicAdd(&pooled[curg * HID_C + 4 * c4 + 1], p1);
        atomicAdd(&pooled[curg * HID_C + 4 * c4 + 2], p2);
        atomicAdd(&pooled[curg * HID_C + 4 * c4 + 3], p3);
    }
}

// ---- mean + FC; one block (64 thr) per graph (unchanged)
__global__ void k_fc(const float* __restrict__ pooled, const int* __restrict__ batch,
                     const float* __restrict__ Wfc, const float* __restrict__ bfc,
                     float* __restrict__ out) {
    int g = blockIdx.x;
    int c = threadIdx.x;
    int lo = 0, hi = N_NODES;
    while (lo < hi) { int mid = (lo + hi) >> 1; if (batch[mid] < g) lo = mid + 1; else hi = mid; }
    int start = lo;
    hi = N_NODES;
    while (lo < hi) { int mid = (lo + hi) >> 1; if (batch[mid] < g + 1) lo = mid + 1; else hi = mid; }
    int n = lo - start;
    float pv = pooled[g * HID_C + c] / (float)(n > 0 ? n : 1);
    float o0 = pv * Wfc[c * OUT_C + 0];
    float o1 = pv * Wfc[c * OUT_C + 1];
#pragma unroll
    for (int off = 32; off > 0; off >>= 1) {
        o0 += __shfl_down(o0, off);
        o1 += __shfl_down(o1, off);
    }
    if (c == 0) {
        out[g * OUT_C + 0] = o0 + bfc[0];
        out[g * OUT_C + 1] = o1 + bfc[1];
    }
}

extern "C" void kernel_launch(void* const* d_in, const int* in_sizes, int n_in,
                              void* d_out, int out_size, void* d_ws, size_t ws_size,
                              hipStream_t stream) {
    const float* x    = (const float*)d_in[0];
    const int*   ei   = (const int*)d_in[1];
    const int*   src  = ei;
    const int*   dst  = ei + N_EDGES;
    const int*   batch= (const int*)d_in[2];
    const float* W1   = (const float*)d_in[3];
    const float* b1   = (const float*)d_in[4];
    const float* W2   = (const float*)d_in[5];
    const float* b2   = (const float*)d_in[6];
    const float* Wfc  = (const float*)d_in[7];
    const float* bfc  = (const float*)d_in[8];
    float* out = (float*)d_out;

    // workspace layout (4B elems)
    float*  ws     = (float*)d_ws;
    int*    bcnt   = (int*)ws;                    // 1024
    float*  pooled = ws + 1024;                   // 16384 (zeroed by k_bscatter)
    float*  dinv   = pooled + 16384;              // 100352
    int*    cnt    = (int*)(dinv + 100352);       // 100352
    int*    rs     = cnt + 100352;                // 100352
    int*    pairs  = rs + 100352;                 // NB*CAPB = 1601536
    int*    csr    = pairs + (NB * CAPB);         // 1601536
    float*  xs     = (float*)(csr + (NB * CAPB)); // N*8 fp32 = 3.2 MB (16B-aligned)
    uint32* g2tab  = (uint32*)(xs + N_NODES * 8); // N*32 uint32 = 12.8 MB

    hipMemsetAsync(bcnt, 0, 1024 * sizeof(int), stream);

    // ---- CSR build + xs = x*dinv (fused) ----
    k_bscatter<<<NBLK_E, 256, 0, stream>>>(src, dst, bcnt, pairs, pooled);
    k_bsort_xs<<<NB, 256, 0, stream>>>(pairs, bcnt, x, csr, rs, cnt, dinv, xs);

    // ---- layer-1: 5-dim gather + @W1 + relu + @W2 (fused; weights in regs) ----
    {
        int blocks = (N_NODES + 4 * L1NPW - 1) / (4 * L1NPW);   // 3125
        k_l1<<<blocks, 256, 0, stream>>>(xs, csr, rs, cnt, dinv, b1, W1, W2, g2tab);
    }

    // ---- layer-2 gather + relu + mean-pool (fused; four nodes per wave) ----
    {
        int waves = (N_NODES + GNPW - 1) / GNPW;     // 12500
        int blocks = (waves + 3) / 4;                // 3125
        k_gather2p<<<blocks, 256, 0, stream>>>(g2tab, csr, rs, cnt, dinv, b2, batch, pooled);
    }

    // ---- FC ----
    k_fc<<<N_GRAPHS, 64, 0, stream>>>(pooled, batch, Wfc, bfc, out);
}

// Round 8
// 201.344 us; speedup vs baseline: 1.3226x; 1.3226x over previous
//
#include <hip/hip_runtime.h>

#define N_NODES 100000
#define N_EDGES 1200000
#define N_GRAPHS 256
#define IN_C 5
#define HID_C 64
#define OUT_C 2

#define BSH 7
#define BNODES 128
#define NB ((N_NODES + BNODES - 1) / BNODES)        // 782
#define CAPB 2048                                   // fixed bucket capacity (E=1534, sigma=39)
#define EPB 2048                                    // edges per block (binning)
#define NBLK_E ((N_EDGES + EPB - 1) / EPB)          // 586
#define GNPW 8                                      // nodes per wave in fused gather2+pool
#define L1NPW 8                                     // nodes per wave in k_l1

typedef unsigned int uint32;

// fp32 -> bf16 round-to-nearest-even (returns 16-bit pattern)
__device__ __forceinline__ uint32 f2bf(float f) {
    uint32 x = __float_as_uint(f);
    return (x + 0x7FFFu + ((x >> 16) & 1u)) >> 16;
}
__device__ __forceinline__ float bflo(uint32 r) { return __uint_as_float(r << 16); }
__device__ __forceinline__ float bfhi(uint32 r) { return __uint_as_float(r & 0xFFFF0000u); }

// ---- bin edges into fixed-capacity bucket regions, packed (dst_local<<17)|src.
// Blocks 0..63 also zero the pooled accumulator (consumed later by k_gather2p).
__global__ void k_bscatter(const int* __restrict__ src, const int* __restrict__ dst,
                           int* __restrict__ bcnt, int* __restrict__ pairs,
                           float* __restrict__ pooled) {
    __shared__ int h[NB];
    if (blockIdx.x < (N_GRAPHS * HID_C) / 256)
        pooled[blockIdx.x * 256 + threadIdx.x] = 0.f;
    for (int i = threadIdx.x; i < NB; i += blockDim.x) h[i] = 0;
    __syncthreads();
    int e0 = blockIdx.x * EPB;
    int e1 = e0 + EPB; if (e1 > N_EDGES) e1 = N_EDGES;
    for (int e = e0 + threadIdx.x; e < e1; e += blockDim.x)
        atomicAdd(&h[dst[e] >> BSH], 1);
    __syncthreads();
    for (int i = threadIdx.x; i < NB; i += blockDim.x)
        if (h[i]) h[i] = (i << 11) + atomicAdd(&bcnt[i], h[i]);
    __syncthreads();
    for (int e = e0 + threadIdx.x; e < e1; e += blockDim.x) {
        int d = dst[e];
        int pos = atomicAdd(&h[d >> BSH], 1);
        pairs[pos] = ((d & (BNODES - 1)) << 17) | src[e];
    }
}

// ---- per-bucket counting sort -> CSR + rs/cnt/dinv, epilogue writes
// xs[node] = x[node] * dinv[node]  (fp32, rows padded to 8 floats).
__global__ void k_bsort_xs(const int* __restrict__ pairs, const int* __restrict__ bcnt,
                           const float* __restrict__ x,
                           int* __restrict__ csr, int* __restrict__ rs,
                           int* __restrict__ cnt, float* __restrict__ dinv,
                           float* __restrict__ xs) {
    __shared__ int hist[BNODES];
    __shared__ int tmp[BNODES];
    __shared__ int cur[BNODES];
    __shared__ float sdv[BNODES];
    int b = blockIdx.x;
    int t = threadIdx.x;
    int base = b << BSH;
    if (t < BNODES) hist[t] = 0;
    __syncthreads();
    int s = b << 11;            // fixed bucket start
    int n = bcnt[b];
    for (int i = t; i < n; i += 256)
        atomicAdd(&hist[pairs[s + i] >> 17], 1);
    __syncthreads();
    int v = (t < BNODES) ? hist[t] : 0;
    if (t < BNODES) tmp[t] = v;
    __syncthreads();
    for (int off = 1; off < BNODES; off <<= 1) {
        int a = (t < BNODES && t >= off) ? tmp[t - off] : 0;
        __syncthreads();
        if (t < BNODES) tmp[t] += a;
        __syncthreads();
    }
    float dv_t = rsqrtf((float)v + 1.0f);
    if (t < BNODES) {
        cur[t] = tmp[t] - v;
        sdv[t] = dv_t;
        if (base + t < N_NODES) {
            rs[base + t] = s + tmp[t] - v;
            cnt[base + t] = v;
            dinv[base + t] = dv_t;
        }
    }
    __syncthreads();
    for (int i = t; i < n; i += 256) {
        int p = pairs[s + i];
        int pos = atomicAdd(&cur[p >> 17], 1);
        csr[s + pos] = p & 0x1FFFF;
    }
    // ---- xs epilogue: xs[node*8+k] = x[node*5+k] * dinv[node], k<5 ----
    for (int i = t; i < BNODES * 8; i += 256) {
        int nl = i >> 3, k = i & 7;
        int node = base + nl;
        if (node < N_NODES && k < IN_C)
            xs[(unsigned)node * 8 + k] = x[(unsigned)node * IN_C + k] * sdv[nl];
    }
}

// ---- fused layer-1: 5-dim gather (L2-resident xs table) + @W1 + relu + @W2,
// writes g2tab (bf16x2 packed). W1/W2 columns live in REGISTERS (each lane
// owns a fixed channel pair), h-row bounces through LDS as broadcast b128 reads.
__global__ void __launch_bounds__(256) k_l1(
        const float* __restrict__ xs, const int* __restrict__ csr,
        const int* __restrict__ rs, const int* __restrict__ cnt,
        const float* __restrict__ dinv, const float* __restrict__ b1,
        const float* __restrict__ W1, const float* __restrict__ W2,
        uint32* __restrict__ g2t) {
    __shared__ __align__(16) float sagg[4][L1NPW][8];   // 1 KB
    __shared__ __align__(16) float srow[4][2][HID_C];   // 2 KB
    int tid = threadIdx.x;
    int w = tid >> 6;
    int lane = tid & 63;
    int base = (blockIdx.x * 4 + w) * L1NPW;

    // ---- gather phase: 8 lanes per node, fp32 5-vec accumulate (pipelined) ----
    int g = lane >> 3, l = lane & 7;
    int v = base + g;
    float a0 = 0.f, a1 = 0.f, a2 = 0.f, a3 = 0.f, a4 = 0.f;
    if (v < N_NODES) {
        int k0 = rs[v];
        int n = cnt[v];
        if (l == 0) {           // self-loop contribution
            float4 p = *(const float4*)&xs[(unsigned)v * 8];
            a0 = p.x; a1 = p.y; a2 = p.z; a3 = p.w;
            a4 = xs[(unsigned)v * 8 + 4];
        }
        int i = l;
        int un = (i < n) ? csr[k0 + i] : -1;
        while (un >= 0) {
            int u = un;
            i += 8;
            un = (i < n) ? csr[k0 + i] : -1;   // next csr overlaps this xs gather
            float4 p = *(const float4*)&xs[(unsigned)u * 8];
            float p4 = xs[(unsigned)u * 8 + 4];
            a0 += p.x; a1 += p.y; a2 += p.z; a3 += p.w; a4 += p4;
        }
    }
#pragma unroll
    for (int off = 4; off; off >>= 1) {
        a0 += __shfl_xor(a0, off);
        a1 += __shfl_xor(a1, off);
        a2 += __shfl_xor(a2, off);
        a3 += __shfl_xor(a3, off);
        a4 += __shfl_xor(a4, off);
    }
    if (l == 0 && v < N_NODES) {
        *(float4*)&sagg[w][g][0] = make_float4(a0, a1, a2, a3);
        sagg[w][g][4] = a4;
    }

    // ---- weight columns -> registers (static indexing only) ----
    int half = lane >> 5, c2 = lane & 31;
    int kb = half << 5;
    float2 w1r[IN_C];
#pragma unroll
    for (int k = 0; k < IN_C; ++k)
        w1r[k] = *(const float2*)&W1[k * HID_C + 2 * c2];
    float2 w2r[32];
#pragma unroll
    for (int j = 0; j < 32; ++j)
        w2r[j] = *(const float2*)&W2[(kb + j) * HID_C + 2 * c2];
    float2 bias = *(const float2*)&b1[2 * c2];

    // ---- dense phase: h1 = relu(dinv*(agg@W1)+b1); g2 = bf16(dinv*(h1@W2)) ----
    for (int gg = 0; gg < L1NPW; ++gg) {
        int node = base + gg;                 // base wave-uniform -> uniform break
        if (node >= N_NODES) break;
        float dv = dinv[node];
        float4 qa = *(const float4*)&sagg[w][gg][0];
        float q4 = sagg[w][gg][4];
        float s0 = qa.x * w1r[0].x + qa.y * w1r[1].x + qa.z * w1r[2].x
                 + qa.w * w1r[3].x + q4 * w1r[4].x;
        float s1 = qa.x * w1r[0].y + qa.y * w1r[1].y + qa.z * w1r[2].y
                 + qa.w * w1r[3].y + q4 * w1r[4].y;
        float h0 = fmaxf(s0 * dv + bias.x, 0.f);
        float h1 = fmaxf(s1 * dv + bias.y, 0.f);
        int buf = gg & 1;
        if (half == 0) *(float2*)&srow[w][buf][2 * c2] = make_float2(h0, h1);
        float t0 = 0.f, t1 = 0.f;
#pragma unroll
        for (int jj = 0; jj < 8; ++jj) {
            float4 hv = *(const float4*)&srow[w][buf][kb + 4 * jj];  // broadcast
            t0 += hv.x * w2r[4 * jj + 0].x + hv.y * w2r[4 * jj + 1].x
                + hv.z * w2r[4 * jj + 2].x + hv.w * w2r[4 * jj + 3].x;
            t1 += hv.x * w2r[4 * jj + 0].y + hv.y * w2r[4 * jj + 1].y
                + hv.z * w2r[4 * jj + 2].y + hv.w * w2r[4 * jj + 3].y;
        }
        t0 += __shfl_xor(t0, 32);
        t1 += __shfl_xor(t1, 32);
        if (half == 0)
            g2t[(unsigned)node * 32 + c2] = (f2bf(t1 * dv) << 16) | f2bf(t0 * dv);
    }
}

// ---- gather layer 2 fused with relu + mean-pool accumulate.
// v4: quad gather kept (4 nodes/wave, 16 lanes each, uint2 loads -> 4 rows /
// instruction in flight), atomic count restored to v2 level via cross-sub
// shuffle merge: when the whole wave's running graph is uniform (~98% of
// waves), reduce p across subs (shfl_xor 16/32) and flush from 16 lanes only.
// v3's per-lane flush was 4x the atomics (WRITE_SIZE 12.7->50.5 MB) with
// 4-way same-address serialization -- the entire 2x regression.
__global__ void __launch_bounds__(256, 4) k_gather2p(
        const uint32* __restrict__ g, const int* __restrict__ csr,
        const int* __restrict__ rs, const int* __restrict__ cnt,
        const float* __restrict__ dinv, const float* __restrict__ b,
        const int* __restrict__ batch, float* __restrict__ pooled) {
    int wv = __builtin_amdgcn_readfirstlane(
        blockIdx.x * (blockDim.x >> 6) + (threadIdx.x >> 6));
    int n0 = wv * GNPW;
    if (n0 >= N_NODES) return;
    int lane = threadIdx.x & 63;
    int sub = lane >> 4;                  // node slot within quad (0..3)
    int c4 = lane & 15;                   // channel-quad index (4 channels)
    float4 bias = *(const float4*)&b[4 * c4];
    float p0 = 0.f, p1 = 0.f, p2 = 0.f, p3 = 0.f;
    int curg = -1;                        // per-lane graph-run accumulator
#pragma unroll
    for (int it = 0; it < GNPW / 4; ++it) {
        int v = n0 + it * 4 + sub;
        int k0 = rs[v];
        int n = cnt[v];
        uint2 rr = *(const uint2*)&g[(unsigned)v * 32 + 2 * c4];   // self-loop
        float s0 = bflo(rr.x), s1 = bfhi(rr.x), s2 = bflo(rr.y), s3 = bfhi(rr.y);
        int i = 0;
        for (; i + 7 < n; i += 8) {
            int u0 = csr[k0 + i + 0], u1 = csr[k0 + i + 1];
            int u2 = csr[k0 + i + 2], u3 = csr[k0 + i + 3];
            int u4 = csr[k0 + i + 4], u5 = csr[k0 + i + 5];
            int u6 = csr[k0 + i + 6], u7 = csr[k0 + i + 7];
            uint2 r0 = *(const uint2*)&g[(unsigned)u0 * 32 + 2 * c4];
            uint2 r1 = *(const uint2*)&g[(unsigned)u1 * 32 + 2 * c4];
            uint2 r2 = *(const uint2*)&g[(unsigned)u2 * 32 + 2 * c4];
            uint2 r3 = *(const uint2*)&g[(unsigned)u3 * 32 + 2 * c4];
            uint2 r4 = *(const uint2*)&g[(unsigned)u4 * 32 + 2 * c4];
            uint2 r5 = *(const uint2*)&g[(unsigned)u5 * 32 + 2 * c4];
            uint2 r6 = *(const uint2*)&g[(unsigned)u6 * 32 + 2 * c4];
            uint2 r7 = *(const uint2*)&g[(unsigned)u7 * 32 + 2 * c4];
            s0 += ((bflo(r0.x) + bflo(r1.x)) + (bflo(r2.x) + bflo(r3.x)))
                + ((bflo(r4.x) + bflo(r5.x)) + (bflo(r6.x) + bflo(r7.x)));
            s1 += ((bfhi(r0.x) + bfhi(r1.x)) + (bfhi(r2.x) + bfhi(r3.x)))
                + ((bfhi(r4.x) + bfhi(r5.x)) + (bfhi(r6.x) + bfhi(r7.x)));
            s2 += ((bflo(r0.y) + bflo(r1.y)) + (bflo(r2.y) + bflo(r3.y)))
                + ((bflo(r4.y) + bflo(r5.y)) + (bflo(r6.y) + bflo(r7.y)));
            s3 += ((bfhi(r0.y) + bfhi(r1.y)) + (bfhi(r2.y) + bfhi(r3.y)))
                + ((bfhi(r4.y) + bfhi(r5.y)) + (bfhi(r6.y) + bfhi(r7.y)));
        }
        for (; i + 3 < n; i += 4) {
            int u0 = csr[k0 + i + 0], u1 = csr[k0 + i + 1];
            int u2 = csr[k0 + i + 2], u3 = csr[k0 + i + 3];
            uint2 r0 = *(const uint2*)&g[(unsigned)u0 * 32 + 2 * c4];
            uint2 r1 = *(const uint2*)&g[(unsigned)u1 * 32 + 2 * c4];
            uint2 r2 = *(const uint2*)&g[(unsigned)u2 * 32 + 2 * c4];
            uint2 r3 = *(const uint2*)&g[(unsigned)u3 * 32 + 2 * c4];
            s0 += (bflo(r0.x) + bflo(r1.x)) + (bflo(r2.x) + bflo(r3.x));
            s1 += (bfhi(r0.x) + bfhi(r1.x)) + (bfhi(r2.x) + bfhi(r3.x));
            s2 += (bflo(r0.y) + bflo(r1.y)) + (bflo(r2.y) + bflo(r3.y));
            s3 += (bfhi(r0.y) + bfhi(r1.y)) + (bfhi(r2.y) + bfhi(r3.y));
        }
        for (; i < n; ++i) {
            uint2 r = *(const uint2*)&g[(unsigned)csr[k0 + i] * 32 + 2 * c4];
            s0 += bflo(r.x); s1 += bfhi(r.x);
            s2 += bflo(r.y); s3 += bfhi(r.y);
        }
        float dv = dinv[v];
        float o0 = fmaxf(s0 * dv + bias.x, 0.f);
        float o1 = fmaxf(s1 * dv + bias.y, 0.f);
        float o2 = fmaxf(s2 * dv + bias.z, 0.f);
        float o3 = fmaxf(s3 * dv + bias.w, 0.f);
        int gg = batch[v];
        if (gg != curg) {
            if (curg >= 0) {              // rare mid-wave graph change
                atomicAdd(&pooled[curg * HID_C + 4 * c4 + 0], p0);
                atomicAdd(&pooled[curg * HID_C + 4 * c4 + 1], p1);
                atomicAdd(&pooled[curg * HID_C + 4 * c4 + 2], p2);
                atomicAdd(&pooled[curg * HID_C + 4 * c4 + 3], p3);
            }
            p0 = 0.f; p1 = 0.f; p2 = 0.f; p3 = 0.f; curg = gg;
        }
        p0 += o0; p1 += o1; p2 += o2; p3 += o3;
    }
    // ---- final flush: merge subs when the wave's graph is uniform ----
    int g0 = __builtin_amdgcn_readfirstlane(curg);
    if (__all(curg == g0)) {
        p0 += __shfl_xor(p0, 16); p0 += __shfl_xor(p0, 32);
        p1 += __shfl_xor(p1, 16); p1 += __shfl_xor(p1, 32);
        p2 += __shfl_xor(p2, 16); p2 += __shfl_xor(p2, 32);
        p3 += __shfl_xor(p3, 16); p3 += __shfl_xor(p3, 32);
        if (sub == 0) {
            atomicAdd(&pooled[g0 * HID_C + 4 * c4 + 0], p0);
            atomicAdd(&pooled[g0 * HID_C + 4 * c4 + 1], p1);
            atomicAdd(&pooled[g0 * HID_C + 4 * c4 + 2], p2);
            atomicAdd(&pooled[g0 * HID_C + 4 * c4 + 3], p3);
        }
    } else {
        atomicAdd(&pooled[curg * HID_C + 4 * c4 + 0], p0);
        atomicAdd(&pooled[curg * HID_C + 4 * c4 + 1], p1);
        atomicAdd(&pooled[curg * HID_C + 4 * c4 + 2], p2);
        atomicAdd(&pooled[curg * HID_C + 4 * c4 + 3], p3);
    }
}

// ---- mean + FC; one block (64 thr) per graph (unchanged)
__global__ void k_fc(const float* __restrict__ pooled, const int* __restrict__ batch,
                     const float* __restrict__ Wfc, const float* __restrict__ bfc,
                     float* __restrict__ out) {
    int g = blockIdx.x;
    int c = threadIdx.x;
    int lo = 0, hi = N_NODES;
    while (lo < hi) { int mid = (lo + hi) >> 1; if (batch[mid] < g) lo = mid + 1; else hi = mid; }
    int start = lo;
    hi = N_NODES;
    while (lo < hi) { int mid = (lo + hi) >> 1; if (batch[mid] < g + 1) lo = mid + 1; else hi = mid; }
    int n = lo - start;
    float pv = pooled[g * HID_C + c] / (float)(n > 0 ? n : 1);
    float o0 = pv * Wfc[c * OUT_C + 0];
    float o1 = pv * Wfc[c * OUT_C + 1];
#pragma unroll
    for (int off = 32; off > 0; off >>= 1) {
        o0 += __shfl_down(o0, off);
        o1 += __shfl_down(o1, off);
    }
    if (c == 0) {
        out[g * OUT_C + 0] = o0 + bfc[0];
        out[g * OUT_C + 1] = o1 + bfc[1];
    }
}

extern "C" void kernel_launch(void* const* d_in, const int* in_sizes, int n_in,
                              void* d_out, int out_size, void* d_ws, size_t ws_size,
                              hipStream_t stream) {
    const float* x    = (const float*)d_in[0];
    const int*   ei   = (const int*)d_in[1];
    const int*   src  = ei;
    const int*   dst  = ei + N_EDGES;
    const int*   batch= (const int*)d_in[2];
    const float* W1   = (const float*)d_in[3];
    const float* b1   = (const float*)d_in[4];
    const float* W2   = (const float*)d_in[5];
    const float* b2   = (const float*)d_in[6];
    const float* Wfc  = (const float*)d_in[7];
    const float* bfc  = (const float*)d_in[8];
    float* out = (float*)d_out;

    // workspace layout (4B elems)
    float*  ws     = (float*)d_ws;
    int*    bcnt   = (int*)ws;                    // 1024
    float*  pooled = ws + 1024;                   // 16384 (zeroed by k_bscatter)
    float*  dinv   = pooled + 16384;              // 100352
    int*    cnt    = (int*)(dinv + 100352);       // 100352
    int*    rs     = cnt + 100352;                // 100352
    int*    pairs  = rs + 100352;                 // NB*CAPB = 1601536
    int*    csr    = pairs + (NB * CAPB);         // 1601536
    float*  xs     = (float*)(csr + (NB * CAPB)); // N*8 fp32 = 3.2 MB (16B-aligned)
    uint32* g2tab  = (uint32*)(xs + N_NODES * 8); // N*32 uint32 = 12.8 MB

    hipMemsetAsync(bcnt, 0, 1024 * sizeof(int), stream);

    // ---- CSR build + xs = x*dinv (fused) ----
    k_bscatter<<<NBLK_E, 256, 0, stream>>>(src, dst, bcnt, pairs, pooled);
    k_bsort_xs<<<NB, 256, 0, stream>>>(pairs, bcnt, x, csr, rs, cnt, dinv, xs);

    // ---- layer-1: 5-dim gather + @W1 + relu + @W2 (fused; weights in regs) ----
    {
        int blocks = (N_NODES + 4 * L1NPW - 1) / (4 * L1NPW);   // 3125
        k_l1<<<blocks, 256, 0, stream>>>(xs, csr, rs, cnt, dinv, b1, W1, W2, g2tab);
    }

    // ---- layer-2 gather + relu + mean-pool (fused; quad gather, merged flush) ----
    {
        int waves = (N_NODES + GNPW - 1) / GNPW;     // 12500
        int blocks = (waves + 3) / 4;                // 3125
        k_gather2p<<<blocks, 256, 0, stream>>>(g2tab, csr, rs, cnt, dinv, b2, batch, pooled);
    }

    // ---- FC ----
    k_fc<<<N_GRAPHS, 64, 0, stream>>>(pooled, batch, Wfc, bfc, out);
}